// Round 27
// baseline (95.707 us; speedup 1.0000x reference)
//
#include <hip/hip_runtime.h>
#include <hip/hip_bf16.h>
#include <hip/hip_fp8.h>
#include <cstdint>
#include <cstddef>

typedef __bf16 bf16;
typedef bf16 bf16x4 __attribute__((ext_vector_type(4)));
typedef bf16 bf16x8 __attribute__((ext_vector_type(8)));
typedef float f32x4 __attribute__((ext_vector_type(4)));
typedef float f32x2 __attribute__((ext_vector_type(2)));
typedef _Float16 h16;

__device__ __forceinline__ float fp8_to_f32(uint8_t b) {
  __hip_fp8_e4m3 t; t.__x = (__hip_fp8_storage_t)b; return (float)t;
}
__device__ __forceinline__ uint8_t f32_to_fp8(float v) {
  __hip_fp8_e4m3 t(v); return (uint8_t)t.__x;
}
__device__ __forceinline__ void cvt4_fp8(int w, float* f) {
#if __has_builtin(__builtin_amdgcn_cvt_pk_f32_fp8)
  f32x2 a = __builtin_amdgcn_cvt_pk_f32_fp8(w, false);
  f32x2 b = __builtin_amdgcn_cvt_pk_f32_fp8(w, true);
  f[0] = a[0]; f[1] = a[1]; f[2] = b[0]; f[3] = b[1];
#else
  f[0] = fp8_to_f32((uint8_t)w);
  f[1] = fp8_to_f32((uint8_t)(w >> 8));
  f[2] = fp8_to_f32((uint8_t)(w >> 16));
  f[3] = fp8_to_f32((uint8_t)(w >> 24));
#endif
}

// ---------------- fused prep (weights, fragment-major) + posm (f16) + LN1 ----------------
__device__ __forceinline__ int kv_perm_to_orig(int j) {
  int jj = j & 255, h = jj >> 5, c = jj & 31;
  return h * 64 + ((j >> 8) ? 32 : 0) + c;
}

__global__ __launch_bounds__(256) void prep_posm_ln_kernel(
    const float* __restrict__ q_w, const float* __restrict__ kv_w,
    const float* __restrict__ proj_w, const float* __restrict__ fc1_w,
    const float* __restrict__ fc2_w, const float* __restrict__ q_b,
    const float* __restrict__ kv_b,
    bf16* __restrict__ wqkvs, bf16* __restrict__ wprojs,
    bf16* __restrict__ wfc1s, bf16* __restrict__ wfc2s,
    float* __restrict__ qscale, float* __restrict__ qbias,
    const int* __restrict__ pe_idx,
    const float* __restrict__ cluster_mask,
    const float* __restrict__ pre_table,
    const float* __restrict__ pe_w, const float* __restrict__ pe_b,
    h16* __restrict__ posm,
    const float* __restrict__ feat,
    const float* __restrict__ norm1_w, const float* __restrict__ norm1_b,
    bf16* __restrict__ xbuf)
{
  const int b = blockIdx.x;
  if (b < 768) {
    int i = b * 256 + threadIdx.x;
    if (i < 196608) {
      // wqkvs: panel(64 cols) x NCH=32 chunks (fn:4,p2:8), K=256
      int e = i & 7, r16 = (i >> 3) & 15, part = (i >> 7) & 3,
          c = (i >> 9) & 31, panel = i >> 14;
      int fn = c >> 3, p2 = c & 7;
      int ncol = panel * 64 + fn * 16 + r16;
      int k = p2 * 32 + part * 8 + e;
      float v;
      if (ncol < 256) v = q_w[(size_t)ncol * 256 + k];
      else            v = kv_w[(size_t)kv_perm_to_orig(ncol - 256) * 256 + k];
      wqkvs[i] = (bf16)v;
    }
    if (i < 65536) {
      // wprojs: panel(32 cols) x NCH=16 chunks (fn:2,p2:8), K=256
      int e = i & 7, r16 = (i >> 3) & 15, part = (i >> 7) & 3,
          c = (i >> 9) & 15, panel = i >> 13;
      int fn = c >> 3, p2 = c & 7;
      int ncol = panel * 32 + fn * 16 + r16;
      int k = p2 * 32 + part * 8 + e;
      wprojs[i] = (bf16)proj_w[(size_t)ncol * 256 + k];
    }
    if (i < 131072) {
      // wfc1s: fn(5b) p2(3b) part(2b) r16(4b) e(3b); K=256
      {
        int e = i & 7, r16 = (i >> 3) & 15, part = (i >> 7) & 3,
            p2 = (i >> 9) & 7, fn = i >> 12;
        wfc1s[i] = (bf16)fc1_w[(size_t)(fn * 16 + r16) * 256 + p2 * 32 + part * 8 + e];
      }
      // wfc2s: fn(4b) p2(4b) part(2b) r16(4b) e(3b); K=512
      {
        int e = i & 7, r16 = (i >> 3) & 15, part = (i >> 7) & 3,
            p2 = (i >> 9) & 15, fn = i >> 13;
        wfc2s[i] = (bf16)fc2_w[(size_t)(fn * 16 + r16) * 512 + p2 * 32 + part * 8 + e];
      }
    }
    if (i < 768) {
      const float s = 0.17677669529663687f;  // 1/sqrt(32)
      if (i < 256) { qscale[i] = s;    qbias[i] = q_b[i] * s; }
      else         { qscale[i] = 1.0f; qbias[i] = kv_b[kv_perm_to_orig(i - 256)]; }
    }
  } else if (b < 2304) {
    int i = (b - 768) * 256 + threadIdx.x;   // (token, j) flat, < 393216
    int pj = pe_idx[i];
    const float* pt = pre_table + (size_t)pj * 5;
    float p0 = pt[0], p1 = pt[1], p2 = pt[2], p3 = pt[3], p4 = pt[4];
    float mk = (1.0f - cluster_mask[i]) * -100.0f;
    h16 v8[8];
    #pragma unroll
    for (int h = 0; h < 8; ++h) {
      float v = p0 * pe_w[h*5+0] + p1 * pe_w[h*5+1] + p2 * pe_w[h*5+2]
              + p3 * pe_w[h*5+3] + p4 * pe_w[h*5+4] + pe_b[h] + mk;
      v8[h] = (h16)v;
    }
    *((uint4*)(posm + (size_t)i * 8)) = *(const uint4*)v8;
  } else {
    // LN1: one wave per 256-elem row (f32 input)
    const int wv = threadIdx.x >> 6, lane = threadIdx.x & 63;
    const int row = (b - 2304) * 4 + wv;
    f32x4 v = *((const f32x4*)(feat + (size_t)row * 256) + lane);
    float s  = v[0] + v[1] + v[2] + v[3];
    float s2 = v[0]*v[0] + v[1]*v[1] + v[2]*v[2] + v[3]*v[3];
    #pragma unroll
    for (int o = 1; o < 64; o <<= 1) { s += __shfl_xor(s, o); s2 += __shfl_xor(s2, o); }
    float mu = s * (1.0f / 256.0f);
    float var = s2 * (1.0f / 256.0f) - mu * mu;
    float rstd = rsqrtf(var + 1e-5f);
    f32x4 wv4 = *((const f32x4*)norm1_w + lane);
    f32x4 bv4 = *((const f32x4*)norm1_b + lane);
    bf16x4 o4;
    o4[0] = (bf16)((v[0] - mu) * rstd * wv4[0] + bv4[0]);
    o4[1] = (bf16)((v[1] - mu) * rstd * wv4[1] + bv4[1]);
    o4[2] = (bf16)((v[2] - mu) * rstd * wv4[2] + bv4[2]);
    o4[3] = (bf16)((v[3] - mu) * rstd * wv4[3] + bv4[3]);
    *((bf16x4*)(xbuf + (size_t)row * 256) + lane) = o4;
  }
}

// ---------------- GEMM: C = A * B^T — fragment-major B, contiguous staging ----------------
template<int NF, int K>
__global__ __launch_bounds__(256) void gemm_bt(
    const bf16* __restrict__ A, const bf16* __restrict__ Bf,
    int N,
    const float* __restrict__ scale, const float* __restrict__ bias,
    const float* __restrict__ residualf, const bf16* __restrict__ residualh,
    int do_gelu,
    float* __restrict__ outf, bf16* __restrict__ outh,
    bf16* __restrict__ outq, uint8_t* __restrict__ outkv)
{
  constexpr int KP = K / 32;
  constexpr int NCH = NF * KP;            // 1KB chunks per panel
  __shared__ __align__(16) bf16 ldsB[NCH * 512];
  const int tid = threadIdx.x;
  const int w = tid >> 6, lane = tid & 63;
  const int part = lane >> 4, r16 = lane & 15;
  const int rowBase = blockIdx.x * 128 + w * 32;
  const int colBase = blockIdx.y * (NF * 16);
  const bf16* Bpanel = Bf + (size_t)blockIdx.y * NCH * 512;

  for (int c = w; c < NCH; c += 4) {
    __builtin_amdgcn_global_load_lds(
        (const __attribute__((address_space(1))) uint32_t*)(Bpanel + c * 512 + lane * 8),
        (__attribute__((address_space(3))) uint32_t*)&ldsB[c * 512], 16, 0, 0);
  }

  f32x4 acc[2][NF] = {};
  const bf16* Aw0 = A + (size_t)(rowBase + r16) * K + part * 8;
  const bf16* Aw1 = A + (size_t)(rowBase + 16 + r16) * K + part * 8;
  __syncthreads();

  #pragma unroll
  for (int p2 = 0; p2 < KP; ++p2) {
    bf16x8 af0 = *(const bf16x8*)(Aw0 + p2 * 32);
    bf16x8 af1 = *(const bf16x8*)(Aw1 + p2 * 32);
    bf16x8 bfr[NF];
    #pragma unroll
    for (int fn = 0; fn < NF; ++fn)
      bfr[fn] = *(const bf16x8*)&ldsB[(fn * KP + p2) * 512 + lane * 8];
    #pragma unroll
    for (int fn = 0; fn < NF; ++fn) {
      acc[0][fn] = __builtin_amdgcn_mfma_f32_16x16x32_bf16(af0, bfr[fn], acc[0][fn], 0, 0, 0);
      acc[1][fn] = __builtin_amdgcn_mfma_f32_16x16x32_bf16(af1, bfr[fn], acc[1][fn], 0, 0, 0);
    }
  }

  #pragma unroll
  for (int fm = 0; fm < 2; ++fm)
  #pragma unroll
  for (int fn = 0; fn < NF; ++fn)
  #pragma unroll
  for (int r = 0; r < 4; ++r) {
    int row = rowBase + fm * 16 + part * 4 + r;
    int col = colBase + fn * 16 + r16;
    float v = acc[fm][fn][r];
    if (scale)     v *= scale[col];
    if (bias)      v += bias[col];
    if (do_gelu)   v = 0.5f * v * (1.0f + erff(v * 0.70710678118654752f));
    if (residualf) v += residualf[(size_t)row * N + col];
    if (residualh) v += (float)residualh[(size_t)row * N + col];
    if (outq) {
      if (col < 256) outq[(size_t)row * 256 + col] = (bf16)v;
      else           outkv[(size_t)row * 512 + (col - 256)] = f32_to_fp8(v);
    } else if (outf) {
      outf[(size_t)row * N + col] = v;
    } else {
      outh[(size_t)row * N + col] = (bf16)v;
    }
  }
}

// ---------------- fused LN2 + MLP, 8 waves/block, fragment-major weights ----------------
__global__ __launch_bounds__(512) void mlp_ln_kernel(
    const bf16* __restrict__ trunk,  // feat2h [8192][256]
    const float* __restrict__ lnw, const float* __restrict__ lnb,
    const bf16* __restrict__ W1s,    // fragment-major [32][8][4][16][8]
    const float* __restrict__ b1,    // [512]
    const bf16* __restrict__ W2s,    // fragment-major [16][16][4][16][8]
    const float* __restrict__ b2,    // [256]
    float* __restrict__ out)         // d_out [8192][256]
{
  __shared__ __align__(16) bf16 xr[16][264];
  __shared__ __align__(16) bf16 y1[16][520];
  const int tid = threadIdx.x;
  const int w = tid >> 6, lane = tid & 63;
  const int part = lane >> 4, r16 = lane & 15;
  const int rowBase = blockIdx.x * 16;

  // phase 0: LN2; wave w handles rows {2w, 2w+1}
  #pragma unroll
  for (int rr = 0; rr < 2; ++rr) {
    const int r = w * 2 + rr;
    bf16x4 vh = *((const bf16x4*)(trunk + (size_t)(rowBase + r) * 256) + lane);
    float v0 = (float)vh[0], v1 = (float)vh[1], v2 = (float)vh[2], v3 = (float)vh[3];
    float s  = v0 + v1 + v2 + v3;
    float s2 = v0*v0 + v1*v1 + v2*v2 + v3*v3;
    #pragma unroll
    for (int o = 1; o < 64; o <<= 1) { s += __shfl_xor(s, o); s2 += __shfl_xor(s2, o); }
    float mu = s * (1.0f / 256.0f);
    float var = s2 * (1.0f / 256.0f) - mu * mu;
    float rstd = rsqrtf(var + 1e-5f);
    f32x4 wv4 = *((const f32x4*)lnw + lane);
    f32x4 bv4 = *((const f32x4*)lnb + lane);
    bf16x4 o4;
    o4[0] = (bf16)((v0 - mu) * rstd * wv4[0] + bv4[0]);
    o4[1] = (bf16)((v1 - mu) * rstd * wv4[1] + bv4[1]);
    o4[2] = (bf16)((v2 - mu) * rstd * wv4[2] + bv4[2]);
    o4[3] = (bf16)((v3 - mu) * rstd * wv4[3] + bv4[3]);
    *((bf16x4*)&xr[r][lane * 4]) = o4;
  }
  __syncthreads();

  // phase 1: y1[16][512] = gelu(xr @ W1^T + b1); wave w -> cols [w*64,+64)
  {
    f32x4 acc[4] = {};
    #pragma unroll
    for (int p2 = 0; p2 < 8; ++p2) {
      bf16x8 af = *(const bf16x8*)&xr[r16][p2 * 32 + part * 8];
      #pragma unroll
      for (int fn = 0; fn < 4; ++fn) {
        const int gfn = w * 4 + fn;
        bf16x8 bf_ = *(const bf16x8*)(W1s + ((size_t)((gfn * 8 + p2) * 4 + part) * 16 + r16) * 8);
        acc[fn] = __builtin_amdgcn_mfma_f32_16x16x32_bf16(af, bf_, acc[fn], 0, 0, 0);
      }
    }
    #pragma unroll
    for (int fn = 0; fn < 4; ++fn)
    #pragma unroll
    for (int r = 0; r < 4; ++r) {
      int row = part * 4 + r;            // 0..15
      int col = w * 64 + fn * 16 + r16;
      float v = acc[fn][r] + b1[col];
      v = 0.5f * v * (1.0f + erff(v * 0.70710678118654752f));
      y1[row][col] = (bf16)v;
    }
  }
  __syncthreads();

  // phase 2: out[16][256] = y1 @ W2^T + b2 + trunk; wave w -> cols [w*32,+32)
  {
    f32x4 acc[2] = {};
    #pragma unroll
    for (int p2 = 0; p2 < 16; ++p2) {
      bf16x8 af = *(const bf16x8*)&y1[r16][p2 * 32 + part * 8];
      #pragma unroll
      for (int fn = 0; fn < 2; ++fn) {
        const int gfn = w * 2 + fn;
        bf16x8 bf_ = *(const bf16x8*)(W2s + ((size_t)((gfn * 16 + p2) * 4 + part) * 16 + r16) * 8);
        acc[fn] = __builtin_amdgcn_mfma_f32_16x16x32_bf16(af, bf_, acc[fn], 0, 0, 0);
      }
    }
    #pragma unroll
    for (int fn = 0; fn < 2; ++fn)
    #pragma unroll
    for (int r = 0; r < 4; ++r) {
      int row = rowBase + part * 4 + r;
      int col = w * 32 + fn * 16 + r16;
      float v = acc[fn][r] + b2[col] + (float)trunk[(size_t)row * 256 + col];
      out[(size_t)row * 256 + col] = v;
    }
  }
}

// ---------------- fused attention + proj: 16 waves/block, one token per wave ----------------
// Grid 512, 1024 threads. Wave w runs the v2b attention body for token tokBase+w,
// writes its output row to LDS ao[w][..]; after one barrier, wave w computes proj
// cols [w*16,+16) for all 16 rows (8 MFMAs, fragment-major wprojs) + bias + f32
// residual(feat) -> feat2h. No attnb round-trip, one fewer dispatch.
__global__ __launch_bounds__(1024) void attn_proj_kernel(
    const bf16* __restrict__ qb,
    const uint8_t* __restrict__ kvf8,
    const int* __restrict__ member_idx,
    const h16* __restrict__ posm,
    const float* __restrict__ blank_k, const float* __restrict__ blank_v,
    const bf16* __restrict__ Wp,      // wprojs fragment-major [8][16][512]
    const float* __restrict__ pbias,  // proj_b
    const float* __restrict__ resid,  // feat (f32)
    bf16* __restrict__ feat2h)
{
  __shared__ __align__(16) bf16 ao[16][264];
  const int tid = threadIdx.x;
  const int w = tid >> 6, lane = tid & 63;
  const int part = lane >> 4, r16 = lane & 15;
  const int bid = blockIdx.x;
  const int xcd = bid & 7, grp = bid >> 3;               // grp in [0,64)
  const int tokBase = (xcd >> 2) * 4096 + (xcd & 3) * 1024 + grp * 16;
  const int token = tokBase + w;
  const int bb = token >> 12;
  const int n = lane >> 4;            // neighbor group 0..3
  const int hc = lane & 15;
  const int h = hc >> 1, cb = hc & 1;
  const int ch0 = h * 32 + cb * 16;   // channel base

  // ---- attention (v2b body, unchanged math) ----
  float q[16];
  {
    const bf16* qrow = qb + (size_t)token * 256 + ch0;
    #pragma unroll
    for (int c8 = 0; c8 < 2; ++c8) {
      bf16x8 t = *(const bf16x8*)(qrow + c8 * 8);
      #pragma unroll
      for (int e = 0; e < 8; ++e) q[c8 * 8 + e] = (float)t[e];
    }
  }

  int   midx[12];
  float pos[12];
  #pragma unroll
  for (int m = 0; m < 12; ++m) {
    midx[m] = member_idx[(size_t)token * 48 + m * 4 + n];
    pos[m]  = (float)posm[(size_t)token * 384 + (m * 4 + n) * 8 + h];
  }

  float l = 0.0f, o[16] = {};
  {  // blank token seeds group n==0
    float db = 0.0f;
    #pragma unroll
    for (int c = 0; c < 16; ++c) db += q[c] * blank_k[ch0 + c];
    db += __shfl_xor(db, 1);
    float pb = __expf(db);
    if (n == 0) {
      l = pb;
      #pragma unroll
      for (int c = 0; c < 16; ++c) o[c] = pb * blank_v[ch0 + c];
    }
  }

  const uint8_t* kvb = kvf8 + (size_t)(bb * 4096) * 512;
  #pragma unroll
  for (int m = 0; m < 12; ++m) {
    const uint8_t* kp = kvb + (size_t)midx[m] * 512 + ch0;
    int4 kw = *(const int4*)kp;          // k[ch0..ch0+15]
    int4 vw = *(const int4*)(kp + 256);  // v[ch0..ch0+15]

    float kf[4];
    float d = 0.0f;
    cvt4_fp8(kw.x, kf);
    #pragma unroll
    for (int c = 0; c < 4; ++c) d += q[c] * kf[c];
    cvt4_fp8(kw.y, kf);
    #pragma unroll
    for (int c = 0; c < 4; ++c) d += q[4 + c] * kf[c];
    cvt4_fp8(kw.z, kf);
    #pragma unroll
    for (int c = 0; c < 4; ++c) d += q[8 + c] * kf[c];
    cvt4_fp8(kw.w, kf);
    #pragma unroll
    for (int c = 0; c < 4; ++c) d += q[12 + c] * kf[c];

    d += __shfl_xor(d, 1);               // combine the two half-channel lanes
    float p = __expf(d + pos[m]);
    l += p;

    float vf[4];
    cvt4_fp8(vw.x, vf);
    #pragma unroll
    for (int c = 0; c < 4; ++c) o[c] += p * vf[c];
    cvt4_fp8(vw.y, vf);
    #pragma unroll
    for (int c = 0; c < 4; ++c) o[4 + c] += p * vf[c];
    cvt4_fp8(vw.z, vf);
    #pragma unroll
    for (int c = 0; c < 4; ++c) o[8 + c] += p * vf[c];
    cvt4_fp8(vw.w, vf);
    #pragma unroll
    for (int c = 0; c < 4; ++c) o[12 + c] += p * vf[c];
  }

  // reduce across the 4 neighbor groups
  l += __shfl_xor(l, 16); l += __shfl_xor(l, 32);
  #pragma unroll
  for (int c = 0; c < 16; ++c) {
    o[c] += __shfl_xor(o[c], 16);
    o[c] += __shfl_xor(o[c], 32);
  }

  if (n == 0) {
    float inv = 1.0f / l;
    #pragma unroll
    for (int c8 = 0; c8 < 2; ++c8) {
      bf16x8 t;
      #pragma unroll
      for (int e = 0; e < 8; ++e) t[e] = (bf16)(o[c8 * 8 + e] * inv);
      *(bf16x8*)&ao[w][ch0 + c8 * 8] = t;
    }
  }
  __syncthreads();

  // ---- proj phase: wave w -> cols [w*16,+16), rows = the block's 16 tokens ----
  {
    f32x4 acc = {};
    const int panel = w >> 1, fn = w & 1;
    const bf16* Wbase = Wp + (size_t)panel * 8192 + (size_t)(fn * 8) * 512;
    #pragma unroll
    for (int p2 = 0; p2 < 8; ++p2) {
      bf16x8 af = *(const bf16x8*)&ao[r16][p2 * 32 + part * 8];
      bf16x8 bf_ = *(const bf16x8*)(Wbase + p2 * 512 + lane * 8);
      acc = __builtin_amdgcn_mfma_f32_16x16x32_bf16(af, bf_, acc, 0, 0, 0);
    }
    #pragma unroll
    for (int r = 0; r < 4; ++r) {
      int row = tokBase + part * 4 + r;
      int col = w * 16 + r16;
      float v = acc[r] + pbias[col] + resid[(size_t)row * 256 + col];
      feat2h[(size_t)row * 256 + col] = (bf16)v;
    }
  }
}

// ---------------- host launcher ----------------
extern "C" void kernel_launch(void* const* d_in, const int* in_sizes, int n_in,
                              void* d_out, int out_size, void* d_ws, size_t ws_size,
                              hipStream_t stream)
{
  (void)in_sizes; (void)n_in; (void)out_size; (void)ws_size;
  const float* feat         = (const float*)d_in[0];
  const float* cluster_mask = (const float*)d_in[1];
  const float* pre_table    = (const float*)d_in[2];
  const float* norm1_w      = (const float*)d_in[3];
  const float* norm1_b      = (const float*)d_in[4];
  const float* q_w    = (const float*)d_in[5];
  const float* q_b    = (const float*)d_in[6];
  const float* kv_w   = (const float*)d_in[7];
  const float* kv_b   = (const float*)d_in[8];
  const float* blank_k = (const float*)d_in[9];
  const float* blank_v = (const float*)d_in[10];
  const float* pe_w   = (const float*)d_in[11];
  const float* pe_b   = (const float*)d_in[12];
  const float* proj_w = (const float*)d_in[13];
  const float* proj_b = (const float*)d_in[14];
  const float* norm2_w = (const float*)d_in[15];
  const float* norm2_b = (const float*)d_in[16];
  const float* fc1_w  = (const float*)d_in[17];
  const float* fc1_b  = (const float*)d_in[18];
  const float* fc2_w  = (const float*)d_in[19];
  const float* fc2_b  = (const float*)d_in[20];
  const int* member_idx = (const int*)d_in[21];
  const int* pe_idx     = (const int*)d_in[22];

  char* ws = (char*)d_ws;
  size_t off = 0;
  auto alloc = [&](size_t bytes) -> void* {
    void* p = ws + off; off += (bytes + 255) & ~(size_t)255; return p;
  };
  bf16*  wqkvs = (bf16*)alloc(768 * 256 * sizeof(bf16));   // fragment-major panels
  bf16*  wprojs = (bf16*)alloc(256 * 256 * sizeof(bf16));  // fragment-major panels
  bf16*  wfc1s = (bf16*)alloc(512 * 256 * sizeof(bf16));   // fragment-major
  bf16*  wfc2s = (bf16*)alloc(256 * 512 * sizeof(bf16));   // fragment-major
  float* qscale = (float*)alloc(768 * sizeof(float));
  float* qbias  = (float*)alloc(768 * sizeof(float));
  bf16*    xbuf   = (bf16*)alloc((size_t)8192 * 256 * sizeof(bf16));
  bf16*    qb     = (bf16*)alloc((size_t)8192 * 256 * sizeof(bf16));
  uint8_t* kvf8   = (uint8_t*)alloc((size_t)8192 * 512);
  bf16*    feat2h = (bf16*)alloc((size_t)8192 * 256 * sizeof(bf16));   // bf16 trunk
  h16*     posm   = (h16*)alloc((size_t)8192 * 48 * 8 * sizeof(h16));
  float* outf = (float*)d_out;

  // 1: prep + posm + LN1 (fused, independent inputs)
  prep_posm_ln_kernel<<<dim3(4352), dim3(256), 0, stream>>>(
      q_w, kv_w, proj_w, fc1_w, fc2_w, q_b, kv_b,
      wqkvs, wprojs, wfc1s, wfc2s, qscale, qbias,
      pe_idx, cluster_mask, pre_table, pe_w, pe_b, posm,
      feat, norm1_w, norm1_b, xbuf);
  // 2: QKV, split epilogue -> q (bf16) + kv (fp8). grid (64,12)=768 blocks
  gemm_bt<4, 256><<<dim3(64, 12), dim3(256), 0, stream>>>(
      xbuf, wqkvs, 768, qscale, qbias,
      (const float*)nullptr, (const bf16*)nullptr, 0,
      (float*)nullptr, (bf16*)nullptr, qb, kvf8);
  // 3: attention + proj + residual (fused) -> feat2h. grid 512 x 1024 threads
  attn_proj_kernel<<<dim3(512), dim3(1024), 0, stream>>>(
      qb, kvf8, member_idx, posm, blank_k, blank_v,
      wprojs, proj_b, feat, feat2h);
  // 4: fused LN2 + MLP (8 waves/block, fragment-major weights) -> d_out
  mlp_ln_kernel<<<dim3(512), dim3(512), 0, stream>>>(
      feat2h, norm2_w, norm2_b, wfc1s, fc1_b, wfc2s, fc2_b, outf);
}

// Round 28
// 84.596 us; speedup vs baseline: 1.1313x; 1.1313x over previous
//
#include <hip/hip_runtime.h>
#include <hip/hip_bf16.h>
#include <hip/hip_fp8.h>
#include <cstdint>
#include <cstddef>

typedef __bf16 bf16;
typedef bf16 bf16x4 __attribute__((ext_vector_type(4)));
typedef bf16 bf16x8 __attribute__((ext_vector_type(8)));
typedef float f32x4 __attribute__((ext_vector_type(4)));
typedef float f32x2 __attribute__((ext_vector_type(2)));
typedef _Float16 h16;

__device__ __forceinline__ float fp8_to_f32(uint8_t b) {
  __hip_fp8_e4m3 t; t.__x = (__hip_fp8_storage_t)b; return (float)t;
}
__device__ __forceinline__ uint8_t f32_to_fp8(float v) {
  __hip_fp8_e4m3 t(v); return (uint8_t)t.__x;
}
__device__ __forceinline__ void cvt4_fp8(int w, float* f) {
#if __has_builtin(__builtin_amdgcn_cvt_pk_f32_fp8)
  f32x2 a = __builtin_amdgcn_cvt_pk_f32_fp8(w, false);
  f32x2 b = __builtin_amdgcn_cvt_pk_f32_fp8(w, true);
  f[0] = a[0]; f[1] = a[1]; f[2] = b[0]; f[3] = b[1];
#else
  f[0] = fp8_to_f32((uint8_t)w);
  f[1] = fp8_to_f32((uint8_t)(w >> 8));
  f[2] = fp8_to_f32((uint8_t)(w >> 16));
  f[3] = fp8_to_f32((uint8_t)(w >> 24));
#endif
}

// ---------------- fused prep (weights, fragment-major) + posm (f16) + LN1 ----------------
// ALL weights FRAGMENT-MAJOR. For a GEMM with CN-col panels and K-dim:
// chunk c=(fn*KP+p2) of panel p is 1024 contiguous bytes: elem (part,r16,e) at
// ((p*NCH + c)*64 + part*16 + r16)*8 + e. One wave B-frag load = 16 lines @100% util.
__device__ __forceinline__ int kv_perm_to_orig(int j) {
  int jj = j & 255, h = jj >> 5, c = jj & 31;
  return h * 64 + ((j >> 8) ? 32 : 0) + c;
}

__global__ __launch_bounds__(256) void prep_posm_ln_kernel(
    const float* __restrict__ q_w, const float* __restrict__ kv_w,
    const float* __restrict__ proj_w, const float* __restrict__ fc1_w,
    const float* __restrict__ fc2_w, const float* __restrict__ q_b,
    const float* __restrict__ kv_b,
    bf16* __restrict__ wqkvs, bf16* __restrict__ wprojs,
    bf16* __restrict__ wfc1s, bf16* __restrict__ wfc2s,
    float* __restrict__ qscale, float* __restrict__ qbias,
    const int* __restrict__ pe_idx,
    const float* __restrict__ cluster_mask,
    const float* __restrict__ pre_table,
    const float* __restrict__ pe_w, const float* __restrict__ pe_b,
    h16* __restrict__ posm,
    const float* __restrict__ feat,
    const float* __restrict__ norm1_w, const float* __restrict__ norm1_b,
    bf16* __restrict__ xbuf)
{
  const int b = blockIdx.x;
  if (b < 768) {
    int i = b * 256 + threadIdx.x;
    if (i < 196608) {
      // wqkvs: panel(64 cols) x NCH=32 chunks (fn:4,p2:8), K=256
      int e = i & 7, r16 = (i >> 3) & 15, part = (i >> 7) & 3,
          c = (i >> 9) & 31, panel = i >> 14;
      int fn = c >> 3, p2 = c & 7;
      int ncol = panel * 64 + fn * 16 + r16;
      int k = p2 * 32 + part * 8 + e;
      float v;
      if (ncol < 256) v = q_w[(size_t)ncol * 256 + k];
      else            v = kv_w[(size_t)kv_perm_to_orig(ncol - 256) * 256 + k];
      wqkvs[i] = (bf16)v;
    }
    if (i < 65536) {
      // wprojs: panel(32 cols) x NCH=16 chunks (fn:2,p2:8), K=256
      int e = i & 7, r16 = (i >> 3) & 15, part = (i >> 7) & 3,
          c = (i >> 9) & 15, panel = i >> 13;
      int fn = c >> 3, p2 = c & 7;
      int ncol = panel * 32 + fn * 16 + r16;
      int k = p2 * 32 + part * 8 + e;
      wprojs[i] = (bf16)proj_w[(size_t)ncol * 256 + k];
    }
    if (i < 131072) {
      // wfc1s: fn(5b) p2(3b) part(2b) r16(4b) e(3b); K=256
      {
        int e = i & 7, r16 = (i >> 3) & 15, part = (i >> 7) & 3,
            p2 = (i >> 9) & 7, fn = i >> 12;
        wfc1s[i] = (bf16)fc1_w[(size_t)(fn * 16 + r16) * 256 + p2 * 32 + part * 8 + e];
      }
      // wfc2s: fn(4b) p2(4b) part(2b) r16(4b) e(3b); K=512
      {
        int e = i & 7, r16 = (i >> 3) & 15, part = (i >> 7) & 3,
            p2 = (i >> 9) & 15, fn = i >> 13;
        wfc2s[i] = (bf16)fc2_w[(size_t)(fn * 16 + r16) * 512 + p2 * 32 + part * 8 + e];
      }
    }
    if (i < 768) {
      const float s = 0.17677669529663687f;  // 1/sqrt(32)
      if (i < 256) { qscale[i] = s;    qbias[i] = q_b[i] * s; }
      else         { qscale[i] = 1.0f; qbias[i] = kv_b[kv_perm_to_orig(i - 256)]; }
    }
  } else if (b < 2304) {
    int i = (b - 768) * 256 + threadIdx.x;   // (token, j) flat, < 393216
    int pj = pe_idx[i];
    const float* pt = pre_table + (size_t)pj * 5;
    float p0 = pt[0], p1 = pt[1], p2 = pt[2], p3 = pt[3], p4 = pt[4];
    float mk = (1.0f - cluster_mask[i]) * -100.0f;
    h16 v8[8];
    #pragma unroll
    for (int h = 0; h < 8; ++h) {
      float v = p0 * pe_w[h*5+0] + p1 * pe_w[h*5+1] + p2 * pe_w[h*5+2]
              + p3 * pe_w[h*5+3] + p4 * pe_w[h*5+4] + pe_b[h] + mk;
      v8[h] = (h16)v;
    }
    *((uint4*)(posm + (size_t)i * 8)) = *(const uint4*)v8;
  } else {
    // LN1: one wave per 256-elem row (f32 input)
    const int wv = threadIdx.x >> 6, lane = threadIdx.x & 63;
    const int row = (b - 2304) * 4 + wv;
    f32x4 v = *((const f32x4*)(feat + (size_t)row * 256) + lane);
    float s  = v[0] + v[1] + v[2] + v[3];
    float s2 = v[0]*v[0] + v[1]*v[1] + v[2]*v[2] + v[3]*v[3];
    #pragma unroll
    for (int o = 1; o < 64; o <<= 1) { s += __shfl_xor(s, o); s2 += __shfl_xor(s2, o); }
    float mu = s * (1.0f / 256.0f);
    float var = s2 * (1.0f / 256.0f) - mu * mu;
    float rstd = rsqrtf(var + 1e-5f);
    f32x4 wv4 = *((const f32x4*)norm1_w + lane);
    f32x4 bv4 = *((const f32x4*)norm1_b + lane);
    bf16x4 o4;
    o4[0] = (bf16)((v[0] - mu) * rstd * wv4[0] + bv4[0]);
    o4[1] = (bf16)((v[1] - mu) * rstd * wv4[1] + bv4[1]);
    o4[2] = (bf16)((v[2] - mu) * rstd * wv4[2] + bv4[2]);
    o4[3] = (bf16)((v[3] - mu) * rstd * wv4[3] + bv4[3]);
    *((bf16x4*)(xbuf + (size_t)row * 256) + lane) = o4;
  }
}

// ---------------- GEMM: C = A * B^T — fragment-major B, contiguous staging ----------------
template<int NF, int K>
__global__ __launch_bounds__(256) void gemm_bt(
    const bf16* __restrict__ A, const bf16* __restrict__ Bf,
    int N,
    const float* __restrict__ scale, const float* __restrict__ bias,
    const float* __restrict__ residualf, const bf16* __restrict__ residualh,
    int do_gelu,
    float* __restrict__ outf, bf16* __restrict__ outh,
    bf16* __restrict__ outq, uint8_t* __restrict__ outkv)
{
  constexpr int KP = K / 32;
  constexpr int NCH = NF * KP;            // 1KB chunks per panel
  __shared__ __align__(16) bf16 ldsB[NCH * 512];
  const int tid = threadIdx.x;
  const int w = tid >> 6, lane = tid & 63;
  const int part = lane >> 4, r16 = lane & 15;
  const int rowBase = blockIdx.x * 128 + w * 32;
  const int colBase = blockIdx.y * (NF * 16);
  const bf16* Bpanel = Bf + (size_t)blockIdx.y * NCH * 512;

  for (int c = w; c < NCH; c += 4) {
    __builtin_amdgcn_global_load_lds(
        (const __attribute__((address_space(1))) uint32_t*)(Bpanel + c * 512 + lane * 8),
        (__attribute__((address_space(3))) uint32_t*)&ldsB[c * 512], 16, 0, 0);
  }

  f32x4 acc[2][NF] = {};
  const bf16* Aw0 = A + (size_t)(rowBase + r16) * K + part * 8;
  const bf16* Aw1 = A + (size_t)(rowBase + 16 + r16) * K + part * 8;
  __syncthreads();

  #pragma unroll
  for (int p2 = 0; p2 < KP; ++p2) {
    bf16x8 af0 = *(const bf16x8*)(Aw0 + p2 * 32);
    bf16x8 af1 = *(const bf16x8*)(Aw1 + p2 * 32);
    bf16x8 bfr[NF];
    #pragma unroll
    for (int fn = 0; fn < NF; ++fn)
      bfr[fn] = *(const bf16x8*)&ldsB[(fn * KP + p2) * 512 + lane * 8];
    #pragma unroll
    for (int fn = 0; fn < NF; ++fn) {
      acc[0][fn] = __builtin_amdgcn_mfma_f32_16x16x32_bf16(af0, bfr[fn], acc[0][fn], 0, 0, 0);
      acc[1][fn] = __builtin_amdgcn_mfma_f32_16x16x32_bf16(af1, bfr[fn], acc[1][fn], 0, 0, 0);
    }
  }

  #pragma unroll
  for (int fm = 0; fm < 2; ++fm)
  #pragma unroll
  for (int fn = 0; fn < NF; ++fn)
  #pragma unroll
  for (int r = 0; r < 4; ++r) {
    int row = rowBase + fm * 16 + part * 4 + r;
    int col = colBase + fn * 16 + r16;
    float v = acc[fm][fn][r];
    if (scale)     v *= scale[col];
    if (bias)      v += bias[col];
    if (do_gelu)   v = 0.5f * v * (1.0f + erff(v * 0.70710678118654752f));
    if (residualf) v += residualf[(size_t)row * N + col];
    if (residualh) v += (float)residualh[(size_t)row * N + col];
    if (outq) {
      if (col < 256) outq[(size_t)row * 256 + col] = (bf16)v;
      else           outkv[(size_t)row * 512 + (col - 256)] = f32_to_fp8(v);
    } else if (outf) {
      outf[(size_t)row * N + col] = v;
    } else {
      outh[(size_t)row * N + col] = (bf16)v;
    }
  }
}

// ---------------- fused LN2 + MLP, 8 waves/block, fragment-major weights ----------------
__global__ __launch_bounds__(512) void mlp_ln_kernel(
    const bf16* __restrict__ trunk,  // feat2h [8192][256]
    const float* __restrict__ lnw, const float* __restrict__ lnb,
    const bf16* __restrict__ W1s,    // fragment-major [32][8][4][16][8]
    const float* __restrict__ b1,    // [512]
    const bf16* __restrict__ W2s,    // fragment-major [16][16][4][16][8]
    const float* __restrict__ b2,    // [256]
    float* __restrict__ out)         // d_out [8192][256]
{
  __shared__ __align__(16) bf16 xr[16][264];
  __shared__ __align__(16) bf16 y1[16][520];
  const int tid = threadIdx.x;
  const int w = tid >> 6, lane = tid & 63;
  const int part = lane >> 4, r16 = lane & 15;
  const int rowBase = blockIdx.x * 16;

  // phase 0: LN2; wave w handles rows {2w, 2w+1}
  #pragma unroll
  for (int rr = 0; rr < 2; ++rr) {
    const int r = w * 2 + rr;
    bf16x4 vh = *((const bf16x4*)(trunk + (size_t)(rowBase + r) * 256) + lane);
    float v0 = (float)vh[0], v1 = (float)vh[1], v2 = (float)vh[2], v3 = (float)vh[3];
    float s  = v0 + v1 + v2 + v3;
    float s2 = v0*v0 + v1*v1 + v2*v2 + v3*v3;
    #pragma unroll
    for (int o = 1; o < 64; o <<= 1) { s += __shfl_xor(s, o); s2 += __shfl_xor(s2, o); }
    float mu = s * (1.0f / 256.0f);
    float var = s2 * (1.0f / 256.0f) - mu * mu;
    float rstd = rsqrtf(var + 1e-5f);
    f32x4 wv4 = *((const f32x4*)lnw + lane);
    f32x4 bv4 = *((const f32x4*)lnb + lane);
    bf16x4 o4;
    o4[0] = (bf16)((v0 - mu) * rstd * wv4[0] + bv4[0]);
    o4[1] = (bf16)((v1 - mu) * rstd * wv4[1] + bv4[1]);
    o4[2] = (bf16)((v2 - mu) * rstd * wv4[2] + bv4[2]);
    o4[3] = (bf16)((v3 - mu) * rstd * wv4[3] + bv4[3]);
    *((bf16x4*)&xr[r][lane * 4]) = o4;
  }
  __syncthreads();

  // phase 1: y1[16][512] = gelu(xr @ W1^T + b1); wave w -> cols [w*64,+64)
  {
    f32x4 acc[4] = {};
    #pragma unroll
    for (int p2 = 0; p2 < 8; ++p2) {
      bf16x8 af = *(const bf16x8*)&xr[r16][p2 * 32 + part * 8];
      #pragma unroll
      for (int fn = 0; fn < 4; ++fn) {
        const int gfn = w * 4 + fn;
        bf16x8 bf_ = *(const bf16x8*)(W1s + ((size_t)((gfn * 8 + p2) * 4 + part) * 16 + r16) * 8);
        acc[fn] = __builtin_amdgcn_mfma_f32_16x16x32_bf16(af, bf_, acc[fn], 0, 0, 0);
      }
    }
    #pragma unroll
    for (int fn = 0; fn < 4; ++fn)
    #pragma unroll
    for (int r = 0; r < 4; ++r) {
      int row = part * 4 + r;            // 0..15
      int col = w * 64 + fn * 16 + r16;
      float v = acc[fn][r] + b1[col];
      v = 0.5f * v * (1.0f + erff(v * 0.70710678118654752f));
      y1[row][col] = (bf16)v;
    }
  }
  __syncthreads();

  // phase 2: out[16][256] = y1 @ W2^T + b2 + trunk; wave w -> cols [w*32,+32)
  {
    f32x4 acc[2] = {};
    #pragma unroll
    for (int p2 = 0; p2 < 16; ++p2) {
      bf16x8 af = *(const bf16x8*)&y1[r16][p2 * 32 + part * 8];
      #pragma unroll
      for (int fn = 0; fn < 2; ++fn) {
        const int gfn = w * 2 + fn;
        bf16x8 bf_ = *(const bf16x8*)(W2s + ((size_t)((gfn * 16 + p2) * 4 + part) * 16 + r16) * 8);
        acc[fn] = __builtin_amdgcn_mfma_f32_16x16x32_bf16(af, bf_, acc[fn], 0, 0, 0);
      }
    }
    #pragma unroll
    for (int fn = 0; fn < 2; ++fn)
    #pragma unroll
    for (int r = 0; r < 4; ++r) {
      int row = rowBase + part * 4 + r;
      int col = w * 32 + fn * 16 + r16;
      float v = acc[fn][r] + b2[col] + (float)trunk[(size_t)row * 256 + col];
      out[(size_t)row * 256 + col] = v;
    }
  }
}

// ---------------- attention v2b + XCD batch-half mapping (champion) ----------------
__global__ __launch_bounds__(256) void attn_kernel(
    const bf16* __restrict__ qb,
    const uint8_t* __restrict__ kvf8,
    const int* __restrict__ member_idx,
    const h16* __restrict__ posm,
    const float* __restrict__ blank_k, const float* __restrict__ blank_v,
    bf16* __restrict__ out)
{
  const int wv = threadIdx.x >> 6, lane = threadIdx.x & 63;
  const int bid = blockIdx.x;
  const int xcd = bid & 7, grp = bid >> 3;               // grp in [0,256)
  const int token = (xcd >> 2) * 4096 + (xcd & 3) * 1024 + grp * 4 + wv;
  const int bb = token >> 12;
  const int n = lane >> 4;            // neighbor group 0..3
  const int hc = lane & 15;
  const int h = hc >> 1, cb = hc & 1;
  const int ch0 = h * 32 + cb * 16;   // channel base

  float q[16];
  {
    const bf16* qrow = qb + (size_t)token * 256 + ch0;
    #pragma unroll
    for (int c8 = 0; c8 < 2; ++c8) {
      bf16x8 t = *(const bf16x8*)(qrow + c8 * 8);
      #pragma unroll
      for (int e = 0; e < 8; ++e) q[c8 * 8 + e] = (float)t[e];
    }
  }

  int   midx[12];
  float pos[12];
  #pragma unroll
  for (int m = 0; m < 12; ++m) {
    midx[m] = member_idx[(size_t)token * 48 + m * 4 + n];
    pos[m]  = (float)posm[(size_t)token * 384 + (m * 4 + n) * 8 + h];
  }

  float l = 0.0f, o[16] = {};
  {  // blank token seeds group n==0
    float db = 0.0f;
    #pragma unroll
    for (int c = 0; c < 16; ++c) db += q[c] * blank_k[ch0 + c];
    db += __shfl_xor(db, 1);
    float pb = __expf(db);
    if (n == 0) {
      l = pb;
      #pragma unroll
      for (int c = 0; c < 16; ++c) o[c] = pb * blank_v[ch0 + c];
    }
  }

  const uint8_t* kvb = kvf8 + (size_t)(bb * 4096) * 512;
  #pragma unroll
  for (int m = 0; m < 12; ++m) {
    const uint8_t* kp = kvb + (size_t)midx[m] * 512 + ch0;
    int4 kw = *(const int4*)kp;          // k[ch0..ch0+15]
    int4 vw = *(const int4*)(kp + 256);  // v[ch0..ch0+15]

    float kf[4];
    float d = 0.0f;
    cvt4_fp8(kw.x, kf);
    #pragma unroll
    for (int c = 0; c < 4; ++c) d += q[c] * kf[c];
    cvt4_fp8(kw.y, kf);
    #pragma unroll
    for (int c = 0; c < 4; ++c) d += q[4 + c] * kf[c];
    cvt4_fp8(kw.z, kf);
    #pragma unroll
    for (int c = 0; c < 4; ++c) d += q[8 + c] * kf[c];
    cvt4_fp8(kw.w, kf);
    #pragma unroll
    for (int c = 0; c < 4; ++c) d += q[12 + c] * kf[c];

    d += __shfl_xor(d, 1);               // combine the two half-channel lanes
    float p = __expf(d + pos[m]);
    l += p;

    float vf[4];
    cvt4_fp8(vw.x, vf);
    #pragma unroll
    for (int c = 0; c < 4; ++c) o[c] += p * vf[c];
    cvt4_fp8(vw.y, vf);
    #pragma unroll
    for (int c = 0; c < 4; ++c) o[4 + c] += p * vf[c];
    cvt4_fp8(vw.z, vf);
    #pragma unroll
    for (int c = 0; c < 4; ++c) o[8 + c] += p * vf[c];
    cvt4_fp8(vw.w, vf);
    #pragma unroll
    for (int c = 0; c < 4; ++c) o[12 + c] += p * vf[c];
  }

  // reduce across the 4 neighbor groups
  l += __shfl_xor(l, 16); l += __shfl_xor(l, 32);
  #pragma unroll
  for (int c = 0; c < 16; ++c) {
    o[c] += __shfl_xor(o[c], 16);
    o[c] += __shfl_xor(o[c], 32);
  }

  if (n == 0) {
    float inv = 1.0f / l;
    bf16* orow = out + (size_t)token * 256 + ch0;
    #pragma unroll
    for (int c8 = 0; c8 < 2; ++c8) {
      bf16x8 t;
      #pragma unroll
      for (int e = 0; e < 8; ++e) t[e] = (bf16)(o[c8 * 8 + e] * inv);
      *(bf16x8*)(orow + c8 * 8) = t;
    }
  }
}

// ---------------- host launcher ----------------
extern "C" void kernel_launch(void* const* d_in, const int* in_sizes, int n_in,
                              void* d_out, int out_size, void* d_ws, size_t ws_size,
                              hipStream_t stream)
{
  (void)in_sizes; (void)n_in; (void)out_size; (void)ws_size;
  const float* feat         = (const float*)d_in[0];
  const float* cluster_mask = (const float*)d_in[1];
  const float* pre_table    = (const float*)d_in[2];
  const float* norm1_w      = (const float*)d_in[3];
  const float* norm1_b      = (const float*)d_in[4];
  const float* q_w    = (const float*)d_in[5];
  const float* q_b    = (const float*)d_in[6];
  const float* kv_w   = (const float*)d_in[7];
  const float* kv_b   = (const float*)d_in[8];
  const float* blank_k = (const float*)d_in[9];
  const float* blank_v = (const float*)d_in[10];
  const float* pe_w   = (const float*)d_in[11];
  const float* pe_b   = (const float*)d_in[12];
  const float* proj_w = (const float*)d_in[13];
  const float* proj_b = (const float*)d_in[14];
  const float* norm2_w = (const float*)d_in[15];
  const float* norm2_b = (const float*)d_in[16];
  const float* fc1_w  = (const float*)d_in[17];
  const float* fc1_b  = (const float*)d_in[18];
  const float* fc2_w  = (const float*)d_in[19];
  const float* fc2_b  = (const float*)d_in[20];
  const int* member_idx = (const int*)d_in[21];
  const int* pe_idx     = (const int*)d_in[22];

  char* ws = (char*)d_ws;
  size_t off = 0;
  auto alloc = [&](size_t bytes) -> void* {
    void* p = ws + off; off += (bytes + 255) & ~(size_t)255; return p;
  };
  bf16*  wqkvs = (bf16*)alloc(768 * 256 * sizeof(bf16));   // fragment-major panels
  bf16*  wprojs = (bf16*)alloc(256 * 256 * sizeof(bf16));  // fragment-major panels
  bf16*  wfc1s = (bf16*)alloc(512 * 256 * sizeof(bf16));   // fragment-major
  bf16*  wfc2s = (bf16*)alloc(256 * 512 * sizeof(bf16));   // fragment-major
  float* qscale = (float*)alloc(768 * sizeof(float));
  float* qbias  = (float*)alloc(768 * sizeof(float));
  bf16*    xbuf   = (bf16*)alloc((size_t)8192 * 256 * sizeof(bf16));
  bf16*    qb     = (bf16*)alloc((size_t)8192 * 256 * sizeof(bf16));
  uint8_t* kvf8   = (uint8_t*)alloc((size_t)8192 * 512);
  bf16*    attnb  = (bf16*)alloc((size_t)8192 * 256 * sizeof(bf16));
  bf16*    feat2h = (bf16*)alloc((size_t)8192 * 256 * sizeof(bf16));   // bf16 trunk
  h16*     posm   = (h16*)alloc((size_t)8192 * 48 * 8 * sizeof(h16));
  float* outf = (float*)d_out;

  // 1: prep + posm + LN1 (fused, independent inputs)
  prep_posm_ln_kernel<<<dim3(4352), dim3(256), 0, stream>>>(
      q_w, kv_w, proj_w, fc1_w, fc2_w, q_b, kv_b,
      wqkvs, wprojs, wfc1s, wfc2s, qscale, qbias,
      pe_idx, cluster_mask, pre_table, pe_w, pe_b, posm,
      feat, norm1_w, norm1_b, xbuf);
  // 2: QKV, split epilogue -> q (bf16) + kv (fp8). grid (64,12)=768 blocks
  gemm_bt<4, 256><<<dim3(64, 12), dim3(256), 0, stream>>>(
      xbuf, wqkvs, 768, qscale, qbias,
      (const float*)nullptr, (const bf16*)nullptr, 0,
      (float*)nullptr, (bf16*)nullptr, qb, kvf8);
  // 3: attention (XCD-partitioned)
  attn_kernel<<<dim3(2048), dim3(256), 0, stream>>>(
      qb, kvf8, member_idx, posm, blank_k, blank_v, attnb);
  // 4: proj + f32 residual(feat) -> feat2h (bf16 trunk). grid (64,8)=512 blocks
  gemm_bt<2, 256><<<dim3(64, 8), dim3(256), 0, stream>>>(
      attnb, wprojs, 256, (const float*)nullptr, proj_b,
      feat, (const bf16*)nullptr, 0,
      (float*)nullptr, feat2h, (bf16*)nullptr, (uint8_t*)nullptr);
  // 5: fused LN2 + MLP (8 waves/block, fragment-major weights) -> d_out
  mlp_ln_kernel<<<dim3(512), dim3(512), 0, stream>>>(
      feat2h, norm2_w, norm2_b, wfc1s, fc1_b, wfc2s, fc2_b, outf);
}